// Round 5
// baseline (642.279 us; speedup 1.0000x reference)
//
#include <hip/hip_runtime.h>
#include <hip/hip_bf16.h>
#include <math.h>

// Problem constants (fixed by setup_inputs)
#define BB 4
#define NN 16384
#define SS 4096
#define D1 128
#define D2 256
#define C1 256   // mlp[0]
#define C2 128   // mlp[1]
#define MTOT (BB*NN)   // 65536

// R12 grid-kNN constants
#define GC 32                  // cells per axis
#define NCELL (GC*GC*GC)       // 32768
#define GLO (-8.0f)            // grid origin (pow2-friendly)
#define GSC 2.0f               // 1/h, h = 0.5
#define GSZ 64                 // candidates per group
#define NG  (SS/GSZ)           // 64 groups per batch
#define SLACK 1e-3f            // covers all fp rounding in d-formula vs bound

typedef _Float16 f16x8 __attribute__((ext_vector_type(8)));
typedef float f32x4  __attribute__((ext_vector_type(4)));

#define LPAD 40            // LDS row stride in fp16 elems (80B, 16B-aligned)

__device__ __forceinline__ int cell_of(float x, float y, float z) {
    int cx = (int)floorf((x - GLO) * GSC);
    int cy = (int)floorf((y - GLO) * GSC);
    int cz = (int)floorf((z - GLO) * GSC);
    cx = min(max(cx, 0), GC - 1);
    cy = min(max(cy, 0), GC - 1);
    cz = min(max(cz, 0), GC - 1);
    return (cz * GC + cy) * GC + cx;
}

// ---------------------------------------------------------------------------
// Convert W1, W2 to fp16 (RNE) once.
// ---------------------------------------------------------------------------
__global__ __launch_bounds__(256) void wcvt_kernel(
    const float* __restrict__ W1, const float* __restrict__ W2,
    _Float16* __restrict__ W1c, _Float16* __restrict__ W2c)
{
    int i = blockIdx.x * 256 + threadIdx.x;
    if (i < C1 * (D1 + D2)) W1c[i] = (_Float16)W1[i];
    if (i < C2 * C1)        W2c[i] = (_Float16)W2[i];
}

// ---------------------------------------------------------------------------
// R12 sort pipeline: per-batch counting sort of candidates (xyz2) and
// queries (xyz1) by 32^3 cell id. Cell choice affects PERF only; all
// correctness rests on the exact bound test + lex compare in knn3_grid.
// ---------------------------------------------------------------------------
__global__ __launch_bounds__(256) void histo_kernel(
    const float* __restrict__ src, int perBatch, unsigned* __restrict__ hist)
{
    int i = blockIdx.x * 256 + threadIdx.x;
    int b = i / perBatch;
    float x = src[(size_t)i*3+0], y = src[(size_t)i*3+1], z = src[(size_t)i*3+2];
    atomicAdd(&hist[(size_t)b * NCELL + cell_of(x, y, z)], 1u);
}

// blocks 0..3: candidate hist -> startC + nextC ; blocks 4..7: query hist -> nextQ
__global__ __launch_bounds__(256) void scan_kernel(
    const unsigned* __restrict__ histC, unsigned* __restrict__ startC,
    unsigned* __restrict__ nextC,
    const unsigned* __restrict__ histQ, unsigned* __restrict__ nextQ)
{
    __shared__ unsigned psum[257];
    const int blk = blockIdx.x;
    const bool isC = blk < 4;
    const int b = isC ? blk : blk - 4;
    const unsigned* h = (isC ? histC : histQ) + (size_t)b * NCELL;
    unsigned* st = isC ? startC + (size_t)b * NCELL : nullptr;
    unsigned* nx = (isC ? nextC : nextQ) + (size_t)b * NCELL;
    const int tid = threadIdx.x;
    const int PB = NCELL / 256;        // 128
    unsigned loc = 0;
    for (int i = 0; i < PB; ++i) loc += h[tid * PB + i];
    psum[tid + 1] = loc;
    __syncthreads();
    if (tid == 0) { psum[0] = 0; for (int i = 1; i <= 256; ++i) psum[i] += psum[i-1]; }
    __syncthreads();
    unsigned run = psum[tid];
    for (int i = 0; i < PB; ++i) {
        unsigned c = h[tid * PB + i];
        if (st) st[tid * PB + i] = run;
        nx[tid * PB + i] = run;
        run += c;
    }
}

// Scatter candidates into sorted order, packing {-2x,-2y,-2z,||p||^2}
// (x(-2) is exact pow2 scaling -> d formula stays BIT-EXACT vs reference).
__global__ __launch_bounds__(256) void scatter_c_kernel(
    const float* __restrict__ xyz2, unsigned* __restrict__ nextC,
    float4* __restrict__ sPk, unsigned short* __restrict__ sIdx)
{
#pragma clang fp contract(off)
    int i = blockIdx.x * 256 + threadIdx.x;
    int b = i >> 12;                  // SS = 4096
    int s = i & (SS - 1);
    float px = xyz2[(size_t)i*3+0], py = xyz2[(size_t)i*3+1], pz = xyz2[(size_t)i*3+2];
    int c = cell_of(px, py, pz);
    unsigned pos = atomicAdd(&nextC[(size_t)b * NCELL + c], 1u);
    float pp = (px*px + py*py) + pz*pz;
    sPk[(size_t)b * SS + pos] = make_float4(-2.0f*px, -2.0f*py, -2.0f*pz, pp);
    sIdx[(size_t)b * SS + pos] = (unsigned short)s;
}

__global__ __launch_bounds__(256) void scatter_q_kernel(
    const float* __restrict__ xyz1, unsigned* __restrict__ nextQ,
    int* __restrict__ qperm)
{
    int i = blockIdx.x * 256 + threadIdx.x;
    int b = i >> 14;                  // NN = 16384
    float x = xyz1[(size_t)i*3+0], y = xyz1[(size_t)i*3+1], z = xyz1[(size_t)i*3+2];
    int c = cell_of(x, y, z);
    unsigned pos = atomicAdd(&nextQ[(size_t)b * NCELL + c], 1u);
    qperm[(size_t)b * NN + pos] = i;  // global query row m
}

// AABB (original coords, exact: x = -0.5 * stored) per group of 64.
__global__ __launch_bounds__(64) void aabb_kernel(
    const float4* __restrict__ sPk, float4* __restrict__ aabb)
{
    int b = blockIdx.x, g = threadIdx.x;
    float mnx = 3.4e38f, mny = 3.4e38f, mnz = 3.4e38f;
    float mxx = -3.4e38f, mxy = -3.4e38f, mxz = -3.4e38f;
    for (int t = 0; t < GSZ; ++t) {
        float4 p = sPk[(size_t)b * SS + g * GSZ + t];
        float x = -0.5f * p.x, y = -0.5f * p.y, z = -0.5f * p.z;
        mnx = fminf(mnx, x); mxx = fmaxf(mxx, x);
        mny = fminf(mny, y); mxy = fmaxf(mxy, y);
        mnz = fminf(mnz, z); mxz = fmaxf(mxz, z);
    }
    aabb[((size_t)b * NG + g) * 2 + 0] = make_float4(mnx, mny, mnz, 0.0f);
    aabb[((size_t)b * NG + g) * 2 + 1] = make_float4(mxx, mxy, mxz, 0.0f);
}

// ---------------------------------------------------------------------------
// R12 grid 3-NN: one lane = one (cell-sorted) query; scan the 64 candidate
// groups in seed-centered zigzag order with exact conservative AABB skip.
// Selection = lexicographic (d, s) insertion == lax.top_k stable order,
// independent of scan order. d formula identical to previous proven code.
// HARD CONSTRAINT (R7): never approximate the distance or the comparison —
// the AABB test only SKIPS groups provably outside e2+SLACK (SLACK >> all
// fp rounding), it never alters d or the compare.
// ---------------------------------------------------------------------------
__global__ __launch_bounds__(128) void knn3_grid_kernel(
    const float* __restrict__ xyz1, const float4* __restrict__ sPk,
    const unsigned short* __restrict__ sIdx, const unsigned* __restrict__ cellStartC,
    const float4* __restrict__ aabb, const int* __restrict__ qperm,
    int* __restrict__ idx_out, float* __restrict__ w_out)
{
#pragma clang fp contract(off)
    __shared__ float4 pk[SS];                      // 64 KB, exactly
    const int tid = threadIdx.x;
    const int b = blockIdx.x >> 7;                 // 128 blocks per batch
    const int qpos = (blockIdx.x & 127) * 128 + tid;

    for (int i = tid; i < SS; i += 128) pk[i] = sPk[(size_t)b * SS + i];
    __syncthreads();

    const int qid = qperm[(size_t)b * NN + qpos];  // global m
    const float qx = xyz1[(size_t)qid*3+0];
    const float qy = xyz1[(size_t)qid*3+1];
    const float qz = xyz1[(size_t)qid*3+2];
    const float qq = (qx*qx + qy*qy) + qz*qz;

    int g0 = min((int)(cellStartC[(size_t)b * NCELL + cell_of(qx, qy, qz)] >> 6), NG - 1);
    g0 = __builtin_amdgcn_readfirstlane(g0);       // wave-uniform seed (perf only)

    float e0 = 3.4e38f, e1 = 3.4e38f, e2 = 3.4e38f;
    int   j0 = 0, j1 = 0, j2 = 0;

    const float4* boxp = aabb + (size_t)b * NG * 2;
    const unsigned short* sidp = sIdx + (size_t)b * SS;

    for (int k = 0; k < NG; ++k) {
        int off = (k + 1) >> 1;
        if (k & 1) off = -off;
        int g = (g0 + off) & (NG - 1);

        float4 mn = boxp[g*2], mx = boxp[g*2+1];
        float dx = fmaxf(fmaxf(mn.x - qx, qx - mx.x), 0.0f);
        float dy = fmaxf(fmaxf(mn.y - qy, qy - mx.y), 0.0f);
        float dz = fmaxf(fmaxf(mn.z - qz, qz - mx.z), 0.0f);
        float bnd = (dx*dx + dy*dy) + dz*dz;
        bool need = bnd < e2 + SLACK;              // e2 sentinel-huge early -> true
        if (__any(need)) {
            const int gb = g * GSZ;
#pragma unroll 4
            for (int t = 0; t < GSZ; ++t) {
                float4 p = pk[gb + t];
                int s = (int)sidp[gb + t];
                float cr2 = (qx*p.x + qy*p.y) + qz*p.z;   // == -2*cr exactly
                float d = (qq + cr2) + p.w;
                d = fmaxf(d, 0.0f);
                // lexicographic (d, s) strict-less vs each kept pair
                bool c0 = (d < e0) || (d == e0 && s < j0);
                bool c1 = (d < e1) || (d == e1 && s < j1);
                bool c2 = (d < e2) || (d == e2 && s < j2);
                j2 = c1 ? j1 : (c2 ? s : j2);
                e2 = c1 ? e1 : (c2 ? d : e2);
                j1 = c0 ? j0 : (c1 ? s : j1);
                e1 = c0 ? e0 : (c1 ? d : e1);
                j0 = c0 ? s : j0;
                e0 = c0 ? d : e0;
            }
        }
    }

    float r0 = 1.0f / (e0 + 1e-8f);
    float r1 = 1.0f / (e1 + 1e-8f);
    float r2 = 1.0f / (e2 + 1e-8f);
    float inv = 1.0f / ((r0 + r1) + r2);
    idx_out[(size_t)qid*3+0] = b * SS + j0;
    idx_out[(size_t)qid*3+1] = b * SS + j1;
    idx_out[(size_t)qid*3+2] = b * SS + j2;
    w_out[(size_t)qid*3+0] = r0 * inv;
    w_out[(size_t)qid*3+1] = r1 * inv;
    w_out[(size_t)qid*3+2] = r2 * inv;
}

// ---------------------------------------------------------------------------
// fp16 MFMA GEMM, LDS double-buffered with ONE barrier per k-iter.
// C[M x N] = op(A[M x K]) @ W[N x K]^T (+ bias).
// Tile 64(M) x 128(N), 4 waves of 32x64, k-chunk 32 (16x16x32 f16 MFMA).
// ---------------------------------------------------------------------------
template<int K, typename AT, typename OT, bool BN_A, bool FUSE_STATS>
__global__ __launch_bounds__(256, 4) void gemm_mfma_kernel(
    const AT* __restrict__ A, int lda,
    const _Float16* __restrict__ W, int ldw,
    OT* __restrict__ C, int ldc,
    const float* __restrict__ bias,
    const float* __restrict__ scaleA, const float* __restrict__ shiftA,
    float* __restrict__ sumO, float* __restrict__ sqO)
{
    __shared__ _Float16 Ash[2][64 * LPAD];     // 2 x 5 KB
    __shared__ _Float16 Bsh[2][128 * LPAD];    // 2 x 10 KB

    const int tid = threadIdx.x;
    const int m0 = blockIdx.x * 64;
    const int n0 = blockIdx.y * 128;
    const int wave = tid >> 6, lane = tid & 63;
    const int ln = lane & 15, q4 = lane >> 4;
    const int wm = wave & 1, wn = wave >> 1;

    const int ar = tid >> 2, ak = (tid & 3) * 8;   // A staging: 64 rows x 32k
    const int br = tid >> 1, bk = (tid & 1) * 16;  // B staging: 128 rows x 32k

    f32x4 acc[2][4] = {};

    float  avF[8];      // used when AT == float
    f16x8  avH;         // used when AT == _Float16
    f16x8  bvA[2];

    {   // prologue prefetch k0 = 0
        if constexpr (__is_same(AT, float)) {
            const float* ap = A + (size_t)(m0 + ar) * lda + ak;
            *(float4*)&avF[0] = *(const float4*)ap;
            *(float4*)&avF[4] = *(const float4*)(ap + 4);
        } else {
            avH = *(const f16x8*)(A + (size_t)(m0 + ar) * lda + ak);
        }
        const _Float16* bp = W + (size_t)(n0 + br) * ldw + bk;
        bvA[0] = *(const f16x8*)bp;
        bvA[1] = *(const f16x8*)(bp + 8);
    }

    for (int k0 = 0; k0 < K; k0 += 32) {
        const int buf = (k0 >> 5) & 1;

        // ---- transform + store staged regs to LDS[buf] ----
        {
            float av[8];
            if constexpr (__is_same(AT, float)) {
#pragma unroll
                for (int i = 0; i < 8; ++i) av[i] = avF[i];
            } else {
#pragma unroll
                for (int i = 0; i < 8; ++i) av[i] = (float)avH[i];
            }
            if (BN_A) {
#pragma unroll
                for (int i = 0; i < 8; ++i) {
                    float sc = scaleA[k0 + ak + i];
                    float sh = shiftA[k0 + ak + i];
                    av[i] = fmaxf(av[i] * sc + sh, 0.0f);
                }
            }
            f16x8 vh;
#pragma unroll
            for (int i = 0; i < 8; ++i) vh[i] = (_Float16)av[i];
            *(f16x8*)&Ash[buf][ar * LPAD + ak] = vh;
            *(f16x8*)&Bsh[buf][br * LPAD + bk]     = bvA[0];
            *(f16x8*)&Bsh[buf][br * LPAD + bk + 8] = bvA[1];
        }
        __syncthreads();    // single barrier: writers of buf done; dbuf makes it safe

        // ---- issue next chunk's global loads (overlap with MFMA below) ----
        if (k0 + 32 < K) {
            if constexpr (__is_same(AT, float)) {
                const float* ap = A + (size_t)(m0 + ar) * lda + (k0 + 32) + ak;
                *(float4*)&avF[0] = *(const float4*)ap;
                *(float4*)&avF[4] = *(const float4*)(ap + 4);
            } else {
                avH = *(const f16x8*)(A + (size_t)(m0 + ar) * lda + (k0 + 32) + ak);
            }
            const _Float16* bp = W + (size_t)(n0 + br) * ldw + (k0 + 32) + bk;
            bvA[0] = *(const f16x8*)bp;
            bvA[1] = *(const f16x8*)(bp + 8);
        }

        // ---- fragments + MFMA ----
        f16x8 af[2];
#pragma unroll
        for (int mi = 0; mi < 2; ++mi) {
            int arow = wm * 32 + mi * 16 + ln;
            af[mi] = *(const f16x8*)&Ash[buf][arow * LPAD + q4 * 8];
        }
        f16x8 bf[4];
#pragma unroll
        for (int ni = 0; ni < 4; ++ni) {
            int brow = wn * 64 + ni * 16 + ln;
            bf[ni] = *(const f16x8*)&Bsh[buf][brow * LPAD + q4 * 8];
        }
#pragma unroll
        for (int mi = 0; mi < 2; ++mi)
#pragma unroll
            for (int ni = 0; ni < 4; ++ni)
                acc[mi][ni] = __builtin_amdgcn_mfma_f32_16x16x32_f16(af[mi], bf[ni], acc[mi][ni], 0, 0, 0);
    }

    // ---- epilogue ----  C/D layout: col = ln, row = q4*4 + r  (m89/m91)
#pragma unroll
    for (int ni = 0; ni < 4; ++ni) {
        int col = n0 + wn * 64 + ni * 16 + ln;
        float vb = bias ? bias[col] : 0.0f;
        float s = 0.0f, s2 = 0.0f;
#pragma unroll
        for (int mi = 0; mi < 2; ++mi) {
#pragma unroll
            for (int r = 0; r < 4; ++r) {
                int row_g = m0 + wm * 32 + mi * 16 + q4 * 4 + r;
                float v = acc[mi][ni][r] + vb;
                C[(size_t)row_g * ldc + col] = (OT)v;
                s += v; s2 += v * v;
            }
        }
        if (FUSE_STATS) {
            s  += __shfl_xor(s, 16);  s  += __shfl_xor(s, 32);
            s2 += __shfl_xor(s2, 16); s2 += __shfl_xor(s2, 32);
            if (q4 == 0) {
                atomicAdd(&sumO[col], s);
                atomicAdd(&sqO[col], s2);
            }
        }
    }
}

// ---------------------------------------------------------------------------
// Dedicated interp + bias + BN1-stats kernel.
// y1[m, :] = temp[m, :] + wa*P2[ia, :] + wb*P2[ib, :] + wc*P2[ic, :] + b1
// ---------------------------------------------------------------------------
__global__ __launch_bounds__(256, 8) void interp_stats_kernel(
    const float* __restrict__ temp,     // [MTOT x C1] fp32 gemm result
    const _Float16* __restrict__ P2,    // [BB*SS x C1] f16
    const int* __restrict__ idx3, const float* __restrict__ w3,
    const float* __restrict__ bias,
    _Float16* __restrict__ Y,           // [MTOT x C1] f16
    float* __restrict__ sumO, float* __restrict__ sqO)
{
    __shared__ float sred[2 * C1];      // 512 floats: [sum | sumsq]
    const int tid = threadIdx.x;
    const int sl  = tid & 31;           // col slice (8 cols)
    const int rg  = tid >> 5;           // 0..7
    const int m0  = blockIdx.x * 32;

    sred[tid] = 0.0f; sred[tid + 256] = 0.0f;
    __syncthreads();

    float bv[8];
    *(float4*)&bv[0] = *(const float4*)(bias + sl * 8);
    *(float4*)&bv[4] = *(const float4*)(bias + sl * 8 + 4);

    float sAcc[8]  = {0.f,0.f,0.f,0.f,0.f,0.f,0.f,0.f};
    float s2Acc[8] = {0.f,0.f,0.f,0.f,0.f,0.f,0.f,0.f};

#pragma unroll
    for (int rr = 0; rr < 4; ++rr) {
        const int row = m0 + rg * 4 + rr;
        const int*   ip = idx3 + (size_t)row * 3;
        const float* wp = w3   + (size_t)row * 3;
        int   ia = ip[0], ib = ip[1], ic = ip[2];
        float wa = wp[0], wb = wp[1], wc = wp[2];

        float av[8];
        const float* tp = temp + (size_t)row * C1 + sl * 8;
        *(float4*)&av[0] = *(const float4*)tp;
        *(float4*)&av[4] = *(const float4*)(tp + 4);
        f16x8 pa = *(const f16x8*)(P2 + (size_t)ia * C1 + sl * 8);
        f16x8 pb = *(const f16x8*)(P2 + (size_t)ib * C1 + sl * 8);
        f16x8 pc = *(const f16x8*)(P2 + (size_t)ic * C1 + sl * 8);

        f16x8 outv;
#pragma unroll
        for (int i = 0; i < 8; ++i) {
            float v = av[i];
            v += wa * (float)pa[i];
            v += wb * (float)pb[i];
            v += wc * (float)pc[i];
            v += bv[i];
            outv[i] = (_Float16)v;
            sAcc[i]  += v;
            s2Acc[i] += v * v;
        }
        *(f16x8*)(Y + (size_t)row * C1 + sl * 8) = outv;
    }

#pragma unroll
    for (int i = 0; i < 8; ++i) {
        atomicAdd(&sred[sl * 8 + i],       sAcc[i]);
        atomicAdd(&sred[256 + sl * 8 + i], s2Acc[i]);
    }
    __syncthreads();
    atomicAdd(&sumO[tid], sred[tid]);
    atomicAdd(&sqO[tid],  sred[tid + 256]);
}

// ---------------------------------------------------------------------------
__global__ void finalize_kernel(
    const float* __restrict__ sum, const float* __restrict__ sumsq,
    const float* __restrict__ g, const float* __restrict__ beta,
    int M, int C, float* __restrict__ scale, float* __restrict__ shift)
{
    int c = threadIdx.x;
    if (c >= C) return;
    float invM = 1.0f / (float)M;
    float mean = sum[c] * invM;
    float var = fmaxf(sumsq[c] * invM - mean * mean, 0.0f);
    float rstd = 1.0f / sqrtf(var + 1e-5f);
    float sc = g[c] * rstd;
    scale[c] = sc;
    shift[c] = beta[c] - mean * sc;
}

__global__ __launch_bounds__(256) void bnrelu_kernel(
    float* __restrict__ X, int total4, int C,
    const float* __restrict__ scale, const float* __restrict__ shift)
{
    int i = blockIdx.x * 256 + threadIdx.x;
    if (i >= total4) return;
    float4 v = ((const float4*)X)[i];
    int c = (i * 4) & (C - 1);      // C pow2, 4 | C -> no wrap within the 4
    v.x = fmaxf(v.x * scale[c+0] + shift[c+0], 0.0f);
    v.y = fmaxf(v.y * scale[c+1] + shift[c+1], 0.0f);
    v.z = fmaxf(v.z * scale[c+2] + shift[c+2], 0.0f);
    v.w = fmaxf(v.w * scale[c+3] + shift[c+3], 0.0f);
    ((float4*)X)[i] = v;
}

// ---------------------------------------------------------------------------
extern "C" void kernel_launch(void* const* d_in, const int* in_sizes, int n_in,
                              void* d_out, int out_size, void* d_ws, size_t ws_size,
                              hipStream_t stream) {
    const float* xyz1    = (const float*)d_in[0];
    const float* xyz2    = (const float*)d_in[1];
    const float* points1 = (const float*)d_in[2];
    const float* points2 = (const float*)d_in[3];
    const float* W1      = (const float*)d_in[4];
    const float* b1      = (const float*)d_in[5];
    const float* g1      = (const float*)d_in[6];
    const float* beta1   = (const float*)d_in[7];
    const float* W2      = (const float*)d_in[8];
    const float* b2      = (const float*)d_in[9];
    const float* g2      = (const float*)d_in[10];
    const float* beta2   = (const float*)d_in[11];
    float* out = (float*)d_out;

    // ws layout (byte offsets, 16B-aligned)
    char* ws = (char*)d_ws;
    size_t off = 0;
    int*   idx = (int*)(ws + off);            off += (size_t)MTOT*3*4;
    float* w   = (float*)(ws + off);          off += (size_t)MTOT*3*4;
    _Float16* P2h = (_Float16*)(ws + off);    off += (size_t)BB*SS*C1*2;    // 8 MB
    _Float16* y1h = (_Float16*)(ws + off);    off += (size_t)MTOT*C1*2;     // 32 MB
    float* stats = (float*)(ws + off);        off += 2048*4;
    float* sum1 = stats;            // 256
    float* sq1  = stats + 256;      // 256
    float* sum2 = stats + 512;      // 128
    float* sq2  = stats + 640;      // 128
    float* scale1 = stats + 768;    // 256
    float* shift1 = stats + 1024;   // 256
    float* scale2 = stats + 1280;   // 128
    float* shift2 = stats + 1408;   // 128
    _Float16* W1c = (_Float16*)(ws + off);    off += (size_t)C1*(D1+D2)*2;
    _Float16* W2c = (_Float16*)(ws + off);    off += (size_t)C2*C1*2;
    off = (off + 255) & ~(size_t)255;
    float* tempf = (float*)(ws + off);        off += (size_t)MTOT*C1*4;     // 64 MB

    // R12 sort-pipeline arrays alias the y1h region (32 MB; y1h is written
    // later, by interp_stats_kernel, after all knn consumers are done).
    char* al = (char*)y1h;
    size_t ao = 0;
    float4* sPk = (float4*)(al + ao);                 ao += (size_t)BB*SS*16;        // 256 KB
    unsigned short* sIdx = (unsigned short*)(al+ao);  ao += (size_t)BB*SS*2;         // 32 KB
    int* qperm = (int*)(al + ao);                     ao += (size_t)BB*NN*4;         // 256 KB
    unsigned* histC = (unsigned*)(al + ao);           ao += (size_t)BB*NCELL*4;      // 512 KB
    unsigned* histQ = (unsigned*)(al + ao);           ao += (size_t)BB*NCELL*4;      // 512 KB
    unsigned* startC = (unsigned*)(al + ao);          ao += (size_t)BB*NCELL*4;      // 512 KB
    unsigned* nextC = (unsigned*)(al + ao);           ao += (size_t)BB*NCELL*4;      // 512 KB
    unsigned* nextQ = (unsigned*)(al + ao);           ao += (size_t)BB*NCELL*4;      // 512 KB
    float4* aabb = (float4*)(al + ao);                ao += (size_t)BB*NG*2*16;      // 8 KB

    hipMemsetAsync(stats, 0, 768 * sizeof(float), stream);
    hipMemsetAsync(histC, 0, (size_t)BB * NCELL * 4 * 2, stream);  // histC + histQ

    wcvt_kernel<<<(C1*(D1+D2))/256, 256, 0, stream>>>(W1, W2, W1c, W2c);

    // ---- sort pipeline ----
    histo_kernel<<<(BB*SS)/256, 256, 0, stream>>>(xyz2, SS, histC);
    histo_kernel<<<(BB*NN)/256, 256, 0, stream>>>(xyz1, NN, histQ);
    scan_kernel<<<8, 256, 0, stream>>>(histC, startC, nextC, histQ, nextQ);
    scatter_c_kernel<<<(BB*SS)/256, 256, 0, stream>>>(xyz2, nextC, sPk, sIdx);
    scatter_q_kernel<<<(BB*NN)/256, 256, 0, stream>>>(xyz1, nextQ, qperm);
    aabb_kernel<<<BB, 64, 0, stream>>>(sPk, aabb);

    // ---- grid 3-NN ----
    knn3_grid_kernel<<<(MTOT)/128, 128, 0, stream>>>(
        xyz1, sPk, sIdx, startC, aabb, qperm, idx, w);

    // P2 = points2 @ W1[:,128:]^T   [B*S x 256], K=256, f16 out
    gemm_mfma_kernel<256, float, _Float16, false, false>
        <<<dim3((BB*SS)/64, C1/128), 256, 0, stream>>>(
        points2, D2, W1c + D1, D1 + D2, P2h, C1,
        nullptr, nullptr, nullptr, nullptr, nullptr);

    // temp = points1 @ W1[:,:128]^T   (plain GEMM, fp32 out, no fusion)
    gemm_mfma_kernel<128, float, float, false, false>
        <<<dim3(MTOT/64, C1/128), 256, 0, stream>>>(
        points1, D1, W1c, D1 + D2, tempf, C1,
        nullptr, nullptr, nullptr, nullptr, nullptr);

    // y1 = temp + interp(P2) + b1  (f16 out) + BN1 stats from fp32
    interp_stats_kernel<<<MTOT/32, 256, 0, stream>>>(
        tempf, P2h, idx, w, b1, y1h, sum1, sq1);

    finalize_kernel<<<1, 256, 0, stream>>>(sum1, sq1, g1, beta1, MTOT, C1, scale1, shift1);

    // out = relu(bn1(y1)) @ W2^T + b2;  fp32 out; fused BN2 stats
    gemm_mfma_kernel<256, _Float16, float, true, true>
        <<<dim3(MTOT/64, C2/128), 256, 0, stream>>>(
        y1h, C1, W2c, C1, out, C2,
        b2, scale1, shift1, sum2, sq2);

    finalize_kernel<<<1, 128, 0, stream>>>(sum2, sq2, g2, beta2, MTOT, C2, scale2, shift2);
    bnrelu_kernel<<<(MTOT*C2/4)/256, 256, 0, stream>>>(out, MTOT*C2/4, C2, scale2, shift2);
}